// Round 1
// baseline (99.511 us; speedup 1.0000x reference)
//
#include <hip/hip_runtime.h>

// SparseNeuralNetwork: 256 independent sub-nets j = i*16 + o (i,o in [0,16)).
//   layer0: v[k] = relu(W0[16j+k, i] * x[b,i] + b0[16j+k]),   k in [0,16)
//   layer1: u[m] = relu(b1[8j+m] + sum_k W1[8j+m, 16j+k] * v[k]), m in [0,8)
//   out[b,o] = b2[o] + sum_i sum_m W2[o, 8j+m] * u[m]
//
// R8 (fusion): single kernel. Each lane = one sub-net j; it gathers its 176
// weights DIRECTLY from W0/W1/W2/b0/b1 (56 vmem ops; b0/b1/W1/W2 rows are
// per-lane-contiguous and quad-contiguous across lanes since lanes 0..3 hold
// consecutive j). This removes prep_kernel, the packT L2 round-trip, the
// workspace, and one graph node. Epilogue: the xor-butterfly leaves the full
// i-sum in EVERY lane, so a per-b cndmask select (i==b) + ONE full-wave
// coalesced store replaces 16 exec-masked 4-lane stores + divergent branches.
// Arithmetic order is bitwise-identical to R7 (absmax 0.0 preserved).
// Grid 2048 waves = 2/SIMD exactly; VGPR ~220 under the 256 cap for 2/SIMD.

#define BATCH   8192
#define IN_DIM  16
#define OUT_DIM 16
#define H0      16
#define H1      8
#define D0      (IN_DIM * OUT_DIM * H0)   // 4096
#define D1      (IN_DIM * OUT_DIM * H1)   // 2048
#define NR      176                        // live weights per sub-net

__global__ __launch_bounds__(64, 2) void mlp_fused(
    const float* __restrict__ x,
    const float* __restrict__ W0, const float* __restrict__ b0,
    const float* __restrict__ W1, const float* __restrict__ b1,
    const float* __restrict__ W2, const float* __restrict__ b2,
    float* __restrict__ out)
{
    const int l  = threadIdx.x;             // 0..63
    const int bx = blockIdx.x;              // 0..2047
    const int og = bx & 3;                  // o-group (4 o's per wave)
    const int bb = (bx >> 2) << 4;          // batch base, 16 elems per wave
    const int i  = l >> 2;                  // input column
    const int o  = (og << 2) | (l & 3);     // output index
    const int j  = (i << 4) | o;            // sub-net id

    // ---- one-time: gather this lane's 176 weights straight from HBM/L2 ----
    // Layout in w[]: [0..15]=W0 col i, [16..31]=b0, [32..159]=W1 rows,
    // [160..167]=b1, [168..175]=W2 row o slice.  (identical to R7 packT)
    float w[NR];

    #pragma unroll
    for (int k = 0; k < H0; ++k)            // 16 scalar loads (stride 64 f)
        w[k] = W0[(j * H0 + k) * IN_DIM + i];

    {   // b0[j*16 .. j*16+15]: 4 float4, quad-contiguous across lanes
        const float4* __restrict__ p = (const float4*)(b0 + j * H0);
        #pragma unroll
        for (int q = 0; q < 4; ++q) {
            const float4 t = p[q];
            w[16 + 4*q] = t.x; w[17 + 4*q] = t.y; w[18 + 4*q] = t.z; w[19 + 4*q] = t.w;
        }
    }
    #pragma unroll
    for (int m = 0; m < H1; ++m) {          // W1 row (j*8+m), cols j*16..+15: 4 float4
        const float4* __restrict__ p =
            (const float4*)(W1 + (size_t)(j * H1 + m) * D0 + j * H0);
        #pragma unroll
        for (int q = 0; q < 4; ++q) {
            const float4 t = p[q];
            const int base = 32 + m * 16 + 4 * q;
            w[base] = t.x; w[base+1] = t.y; w[base+2] = t.z; w[base+3] = t.w;
        }
    }
    {   // b1[j*8 .. j*8+7]: 2 float4
        const float4* __restrict__ p = (const float4*)(b1 + j * H1);
        #pragma unroll
        for (int q = 0; q < 2; ++q) {
            const float4 t = p[q];
            w[160 + 4*q] = t.x; w[161 + 4*q] = t.y; w[162 + 4*q] = t.z; w[163 + 4*q] = t.w;
        }
    }
    {   // W2[o, j*8 .. j*8+7]: 2 float4
        const float4* __restrict__ p = (const float4*)(W2 + o * D1 + j * H1);
        #pragma unroll
        for (int q = 0; q < 2; ++q) {
            const float4 t = p[q];
            w[168 + 4*q] = t.x; w[169 + 4*q] = t.y; w[170 + 4*q] = t.z; w[171 + 4*q] = t.w;
        }
    }

    // ---- x preload: this lane's input column i, 16 batch elems ----
    float xi[16];
    const float* __restrict__ xp = x + (size_t)bb * IN_DIM + i;
    #pragma unroll
    for (int b = 0; b < 16; ++b) xi[b] = xp[b * IN_DIM];

    const float b2v = b2[o];

    // ---- register-resident compute, 16 batch elems ----
    float myres = 0.0f;
    #pragma unroll
    for (int b = 0; b < 16; ++b) {
        float v[H0];
        #pragma unroll
        for (int k = 0; k < H0; ++k)
            v[k] = fmaxf(fmaf(w[k], xi[b], w[16 + k]), 0.0f);

        float acc = 0.0f;
        #pragma unroll
        for (int m = 0; m < H1; ++m) {
            float u = w[160 + m];
            #pragma unroll
            for (int k = 0; k < H0; ++k)
                u = fmaf(w[32 + m * 16 + k], v[k], u);
            acc = fmaf(w[168 + m], fmaxf(u, 0.0f), acc);
        }

        // butterfly over i (lane bits 2..5); EVERY lane ends with the full sum
        acc += __shfl_xor(acc, 4, 64);
        acc += __shfl_xor(acc, 8, 64);
        acc += __shfl_xor(acc, 16, 64);
        acc += __shfl_xor(acc, 32, 64);

        // keep the result whose batch row this lane will store (i == b)
        myres = (i == b) ? acc : myres;
    }

    // one full-wave store: lane l writes out[bb+i, o] (16 B segments, 1 instr)
    out[(size_t)(bb + i) * OUT_DIM + o] = myres + b2v;
}

extern "C" void kernel_launch(void* const* d_in, const int* in_sizes, int n_in,
                              void* d_out, int out_size, void* d_ws, size_t ws_size,
                              hipStream_t stream) {
    const float* x  = (const float*)d_in[0];
    const float* W0 = (const float*)d_in[1];
    const float* b0 = (const float*)d_in[2];
    const float* W1 = (const float*)d_in[3];
    const float* b1 = (const float*)d_in[4];
    const float* W2 = (const float*)d_in[5];
    const float* b2 = (const float*)d_in[6];
    float* out = (float*)d_out;
    (void)d_ws; (void)ws_size;              // workspace no longer used

    // 2048 blocks x 1 wave: og = bx&3, batch chunk = bx>>2 (16 elems each)
    mlp_fused<<<2048, 64, 0, stream>>>(x, W0, b0, W1, b1, W2, b2, out);
}